// Round 2
// baseline (518.896 us; speedup 1.0000x reference)
//
#include <hip/hip_runtime.h>
#include <cmath>

#define GH 384
#define GW 384
#define GN 32
#define C4 4            // float4 groups per pixel (16 channels)
#define RAD 6
#define KS 13
#define TW 32           // tile width (pixels)
#define TH 16           // tile height (output rows)
#define LROWS (TH + 2*RAD)   // 28 intermediate rows
#define PXH 8           // phase-1: pixels per horizontal strip task
#define PYV 8           // phase-2: output rows per thread

struct Wt13 { float w[KS]; };

__global__ __launch_bounds__(256)
void gauss13_kernel(const float4* __restrict__ x, float4* __restrict__ y, Wt13 wt) {
    // intermediate: horizontally-blurred rows [h0-6, h0+TH+6) x TW cols x 16ch
    __shared__ float4 lds[LROWS][TW][C4];   // 28*32*4*16B = 57344 B -> 2 blocks/CU

    const int tid = threadIdx.x;
    const int w0 = blockIdx.x * TW;
    const int h0 = blockIdx.y * TH;
    const int n  = blockIdx.z;

    // ---------- phase 1: horizontal blur -> LDS ----------
    // task = (c4, colg, lrow); 8-pixel sliding window in registers:
    // 20 float4 global loads produce 8 horizontally-blurred float4s.
    {
        const int c4    = tid & 3;
        const int colg  = (tid >> 2) & 3;       // 4 col-groups of 8
        const int lrow0 = tid >> 4;             // 0..15
        #pragma unroll
        for (int it = 0; it < 2; ++it) {
            const int lrow = lrow0 + it * 16;   // 0..31, skip >= 28
            if (lrow < LROWS) {
                const int gr = h0 - RAD + lrow; // global row (may be OOB -> zeros)
                float4 ld[PXH + 2*RAD];
                if (gr >= 0 && gr < GH) {
                    const float4* rowp = x + (size_t)(n * GH + gr) * GW * C4 + c4;
                    #pragma unroll
                    for (int k = 0; k < PXH + 2*RAD; ++k) {
                        const int gw = w0 + colg * PXH - RAD + k;
                        ld[k] = (gw >= 0 && gw < GW) ? rowp[(size_t)gw * C4]
                                                     : make_float4(0.f, 0.f, 0.f, 0.f);
                    }
                } else {
                    #pragma unroll
                    for (int k = 0; k < PXH + 2*RAD; ++k)
                        ld[k] = make_float4(0.f, 0.f, 0.f, 0.f);
                }
                #pragma unroll
                for (int p = 0; p < PXH; ++p) {
                    float sx = 0.f, sy = 0.f, sz = 0.f, sw = 0.f;
                    #pragma unroll
                    for (int k = 0; k < KS; ++k) {
                        const float g = wt.w[k];
                        sx += ld[p + k].x * g;
                        sy += ld[p + k].y * g;
                        sz += ld[p + k].z * g;
                        sw += ld[p + k].w * g;
                    }
                    lds[lrow][colg * PXH + p][c4] = make_float4(sx, sy, sz, sw);
                }
            }
        }
    }
    __syncthreads();

    // ---------- phase 2: vertical blur from LDS -> global ----------
    // thread = (c4, col, row-chunk of 8); 20 ds_read_b128 -> 8 outputs.
    {
        const int c4  = tid & 3;
        const int col = (tid >> 2) & 31;
        const int r0  = (tid >> 7) * PYV;       // 0 or 8
        float4 acc[PYV];
        #pragma unroll
        for (int i = 0; i < PYV; ++i) acc[i] = make_float4(0.f, 0.f, 0.f, 0.f);
        #pragma unroll
        for (int t = 0; t < PYV + 2*RAD; ++t) { // 20 taps
            const float4 v = lds[r0 + t][col][c4];
            #pragma unroll
            for (int i = 0; i < PYV; ++i) {
                const int k = t - i;            // weight index, compile-time resolved
                if (k >= 0 && k < KS) {
                    const float g = wt.w[k];
                    acc[i].x += v.x * g;
                    acc[i].y += v.y * g;
                    acc[i].z += v.z * g;
                    acc[i].w += v.w * g;
                }
            }
        }
        float4* outp = y + ((size_t)(n * GH + h0 + r0) * GW + (w0 + col)) * C4 + c4;
        #pragma unroll
        for (int i = 0; i < PYV; ++i)
            outp[(size_t)i * GW * C4] = acc[i];
    }
}

extern "C" void kernel_launch(void* const* d_in, const int* in_sizes, int n_in,
                              void* d_out, int out_size, void* d_ws, size_t ws_size,
                              hipStream_t stream) {
    const float4* x = (const float4*)d_in[0];
    float4* y = (float4*)d_out;

    // separable 1D weights: g/sum(g) per dim (outer(k,k)/sum == outer(g/s, g/s))
    Wt13 wt;
    double g[KS], s = 0.0;
    for (int i = 0; i < KS; ++i) { double d = i - 6.0; g[i] = exp(-(d * d) / 8.0); s += g[i]; }
    for (int i = 0; i < KS; ++i) wt.w[i] = (float)(g[i] / s);

    dim3 grid(GW / TW, GH / TH, GN);   // (12, 24, 32)
    gauss13_kernel<<<grid, 256, 0, stream>>>(x, y, wt);
}